// Round 7
// baseline (319.227 us; speedup 1.0000x reference)
//
#include <hip/hip_runtime.h>

typedef short short8 __attribute__((ext_vector_type(8)));
typedef float f32x4 __attribute__((ext_vector_type(4)));

constexpr int Bc = 2, Hc = 16, NQc = 1024, NKc = 1024, DHc = 128;
constexpr int BQ = 16;
constexpr int PBP = 1032;                    // p-bf16 LDS pitch (shorts); rows 16B-aligned
constexpr size_t KBF_ELEMS = (size_t)Bc * Hc * NKc * DHc;   // 4,194,304 shorts

#define BARRIER() __builtin_amdgcn_s_barrier()
#define WAITV(n) asm volatile("s_waitcnt vmcnt(" #n ")" ::: "memory")
#define WAITL0() asm volatile("s_waitcnt lgkmcnt(0)" ::: "memory")
#define SCHED0() __builtin_amdgcn_sched_barrier(0)

__device__ __forceinline__ unsigned cvtpk(float a, float b) {  // HW RNE f32x2 -> bf16x2
  unsigned r;
  asm("v_cvt_pk_bf16_f32 %0, %1, %2" : "=v"(r) : "v"(a), "v"(b));
  return r;
}
__device__ __forceinline__ unsigned long long pack4(float a, float b, float c, float d) {
  return (unsigned long long)cvtpk(a, b) | ((unsigned long long)cvtpk(c, d) << 32);
}
__device__ __forceinline__ float bfbits(unsigned u) {  // u must be (bf16 << 16)
  union { unsigned x; float f; } w; w.x = u; return w.f;
}

typedef __attribute__((address_space(1))) const unsigned int glb_u32;
typedef __attribute__((address_space(3))) unsigned int lds_u32;
__device__ __forceinline__ void gl16(const void* g, void* l) {
  __builtin_amdgcn_global_load_lds((glb_u32*)g, (lds_u32*)l, 16, 0, 0);
}

// ---------------- pre-pass: K -> bf16, V -> V^T bf16 ----------------
__global__ __launch_bounds__(256) void prep(const float* __restrict__ km,
                                            const float* __restrict__ vm,
                                            unsigned short* __restrict__ kbf,
                                            unsigned short* __restrict__ vtb) {
  const int blk = blockIdx.x, t = threadIdx.x;
  if (blk < 1024) {
    // V^T: 64x64 tile transpose per block. 32 bh * (16 k-tiles x 2 d-tiles)
    __shared__ float tile[64][65];
    const int bh = blk >> 5, tl = blk & 31;
    const int k0 = (tl & 15) * 64, d0 = (tl >> 4) * 64;
    const float* vsrc = vm + ((size_t)bh * NKc + k0) * DHc + d0;
    {
      int j = t & 63, i0 = t >> 6;
#pragma unroll
      for (int s = 0; s < 16; ++s) {
        int i = i0 + s * 4;
        tile[i][j] = vsrc[(size_t)i * DHc + j];
      }
    }
    __syncthreads();
    unsigned short* vdst = vtb + ((size_t)bh * DHc + d0) * NKc + k0;
    {
      int i2 = (t & 15) * 4, j0 = t >> 4;
#pragma unroll
      for (int s = 0; s < 4; ++s) {
        int j2 = j0 + s * 16;
        float a0 = tile[i2 + 0][j2], a1 = tile[i2 + 1][j2];
        float a2 = tile[i2 + 2][j2], a3 = tile[i2 + 3][j2];
        *(unsigned long long*)(vdst + (size_t)j2 * NKc + i2) = pack4(a0, a1, a2, a3);
      }
    }
  } else {
    const float4* kf4 = (const float4*)km;
#pragma unroll
    for (int rep = 0; rep < 2; ++rep) {
      size_t g = (size_t)(blk - 1024) * 256 + t + (size_t)rep * 524288;
      float4 f = kf4[g];
      *(unsigned long long*)(kbf + g * 4) = pack4(f.x, f.y, f.z, f.w);
    }
  }
}

// ---------------- main fused attention (double-buffered, counted vmcnt) ----------------
__global__ __launch_bounds__(512, 2) void attn_main(
    const float* __restrict__ qm, const unsigned short* __restrict__ kbf,
    const unsigned short* __restrict__ vtb,
    const float* __restrict__ dq, const float* __restrict__ dkt, const float* __restrict__ dkb,
    const float* __restrict__ dks, const float* __restrict__ ww, const float* __restrict__ bw,
    const float* __restrict__ wb, const float* __restrict__ bb,
    float* __restrict__ outp, float* __restrict__ pp)
{
  __shared__ __align__(16) unsigned short kv[2][16384];    // 64 KB double-buffered chunk
  __shared__ __align__(16) unsigned short pbs[BQ * PBP];   // 33 KB p bf16
  __shared__ float e0s[1024], cws[1024], cbs[1024];        // 12 KB gate scalars
  __shared__ float aws[BQ], abs_[BQ];
  __shared__ float redm[128], redl[128];
  // total ~110 KB -> 1 block/CU (intentional: counted-vmcnt pipeline instead of TLP)

  const int wg = blockIdx.x;
  const int bid = (wg & 7) * 256 + (wg >> 3);   // bijective XCD swizzle (2048 % 8 == 0)
  const int qt = bid & 63, h = (bid >> 6) & 15, b = bid >> 10;
  const int q0 = qt * BQ;
  const int t = threadIdx.x, wv = t >> 6, lane = t & 63;
  const int hi = lane >> 4, lo = lane & 15;
  const int rb = hi << 2;
  const int bh = b * Hc + h;

  // ---- gate scalar precompute ----
  {
    float whc[8], wbc[8];
#pragma unroll
    for (int d = 0; d < 8; ++d) { whc[d] = ww[d * Hc + h]; wbc[d] = wb[d * Hc + h]; }
    float bwh = bw[h], bbh = bb[h];
#pragma unroll
    for (int rep = 0; rep < 2; ++rep) {
      int kk = t + rep * 512;
      const float* sc = dks + ((size_t)b * NKc + kk) * 2;
      float s0 = sc[0], s1 = sc[1];
      const float* tp = dkt + ((size_t)b * NKc + kk) * 8;
      const float* bp = dkb + ((size_t)b * NKc + kk) * 8;
      float4 t0 = *(const float4*)tp, t1 = *(const float4*)(tp + 4);
      float4 b0 = *(const float4*)bp, b1 = *(const float4*)(bp + 4);
      float tv[8] = {t0.x, t0.y, t0.z, t0.w, t1.x, t1.y, t1.z, t1.w};
      float bv[8] = {b0.x, b0.y, b0.z, b0.w, b1.x, b1.y, b1.z, b1.w};
      float cw = 0.f, cb = 0.f;
#pragma unroll
      for (int d = 0; d < 8; ++d) {
        float dk = tv[d] * s0 + bv[d] * s1;
        cw += dk * whc[d];
        cb += dk * wbc[d];
      }
      e0s[kk] = s0 + s1;
      cws[kk] = cw - bwh;
      cbs[kk] = cb - bbh;
    }
    if (t < BQ) {
      const float* dqr = dq + ((size_t)b * NQc + q0 + t) * 8;
      float4 a = *(const float4*)dqr, b4 = *(const float4*)(dqr + 4);
      float dv[8] = {a.x, a.y, a.z, a.w, b4.x, b4.y, b4.z, b4.w};
      float saw = 0.f, sab = 0.f;
#pragma unroll
      for (int d = 0; d < 8; ++d) { saw += dv[d] * whc[d]; sab += dv[d] * wbc[d]; }
      aws[t] = saw; abs_[t] = sab;
    }
  }

  // ---- Q fragments direct from global fp32 (A[m=lo][k = kk*32 + hi*8 + j]) ----
  short8 qf[4];
  {
    const float* qg = qm + ((size_t)bh * NQc + q0 + lo) * DHc + hi * 8;
#pragma unroll
    for (int kk = 0; kk < 4; ++kk) {
      float4 a = *(const float4*)(qg + kk * 32);
      float4 c = *(const float4*)(qg + kk * 32 + 4);
      union { short8 v; unsigned long long u[2]; } q8;
      q8.u[0] = pack4(a.x, a.y, a.z, a.w);
      q8.u[1] = pack4(c.x, c.y, c.z, c.w);
      qf[kk] = q8.v;
    }
  }

  const float scale = 0.08838834764831845f;  // 1/sqrt(128)
  const unsigned short* kg = kbf + (size_t)bh * NKc * DHc;
  const unsigned short* vtg = vtb + (size_t)bh * DHc * NKc;

  // ---- hoisted per-lane staging descriptors & MFMA LDS offsets ----
  const unsigned short* ksrc[4];   // K chunk src (without kc term)
  const unsigned short* vsrc[4];   // V^T chunk src (without vc term)
  int boff[4];                     // wave-uniform LDS dest byte offsets (within one buffer)
#pragma unroll
  for (int r = 0; r < 4; ++r) {
    int base = ((r << 3) + wv) << 10;          // wave-uniform dest byte base
    int F = base + (lane << 4);
    int kr = F >> 8;                            // dest row (key or d-dim)
    int gslot = ((F >> 4) & 15) ^ (kr & 15);    // inverse-swizzled source slot
    ksrc[r] = kg + ((size_t)kr << 7) + (gslot << 3);
    vsrc[r] = vtg + ((size_t)kr << 10) + (gslot << 3);
    boff[r] = base;
  }
  const int kr16 = (wv << 4) + lo;              // B-frag n (key idx / d idx)
  int qoff[4];                                  // swizzled B-frag LDS offsets (shorts)
#pragma unroll
  for (int kk = 0; kk < 4; ++kk)
    qoff[kk] = (kr16 << 7) + (((((kk << 2) + hi)) ^ (kr16 & 15)) << 3);

  __syncthreads();   // full drain: fences gate scalars + all prologue VMEM
  float aw4[4], ab4[4];
#pragma unroll
  for (int i = 0; i < 4; ++i) { aw4[i] = aws[rb + i]; ab4[i] = abs_[rb + i]; }

  // ---- pipeline prologue: issue chunks 0 and 1 ----
#pragma unroll
  for (int r = 0; r < 4; ++r) gl16(ksrc[r], (char*)&kv[0][0] + boff[r]);
#pragma unroll
  for (int r = 0; r < 4; ++r) gl16(ksrc[r] + (1 << 14), (char*)&kv[1][0] + boff[r]);

  // ---- Phase 1: QK^T + gate; loads for chunk c+1 stay in flight across compute of c ----
  f32x4 sacc[8];
#pragma unroll 1
  for (int kc = 0; kc < 8; ++kc) {
    const int cur = kc & 1;
    WAITV(4); SCHED0();          // chunk kc landed (kc+1 still in flight)
    BARRIER();                   // all waves' loads for kc landed
    f32x4 acc = {0.f, 0.f, 0.f, 0.f};
#pragma unroll
    for (int kk = 0; kk < 4; ++kk)
      acc = __builtin_amdgcn_mfma_f32_16x16x32_bf16(qf[kk], *(const short8*)&kv[cur][qoff[kk]], acc, 0, 0, 0);
    int cg = (kc << 7) + kr16;
    float e0 = e0s[cg], cw2 = cws[cg], cb2 = cbs[cg];
#pragma unroll
    for (int i = 0; i < 4; ++i) {
      float s = acc[i] * scale;
      float x = fmaf(e0, aw4[i], -cw2);
      float ex = __expf(x);
      float sp = (x > 20.f) ? x : __logf(1.f + ex);   // softplus, cheap form
      acc[i] = fmaf(s, sp, fmaf(e0, ab4[i], -cb2));
    }
    sacc[kc] = acc;
    WAITL0(); SCHED0();          // my LDS reads of kv[cur] complete
    BARRIER();                   // everyone done reading kv[cur]
    if (kc < 6) {
#pragma unroll
      for (int r = 0; r < 4; ++r) gl16(ksrc[r] + ((size_t)(kc + 2) << 14), (char*)&kv[cur][0] + boff[r]);
    } else {
      int vc0 = kc - 6;          // V chunks 0,1
#pragma unroll
      for (int r = 0; r < 4; ++r) gl16(vsrc[r] + (vc0 << 7), (char*)&kv[cur][0] + boff[r]);
    }
  }

  // ---- Phase 2: exact softmax over registers (raw barriers: no vmcnt drain) ----
  float m4[4], inv4[4];
#pragma unroll
  for (int i = 0; i < 4; ++i) {
    float pm = sacc[0][i];
#pragma unroll
    for (int kc = 1; kc < 8; ++kc) pm = fmaxf(pm, sacc[kc][i]);
    pm = fmaxf(pm, __shfl_xor(pm, 1, 64));
    pm = fmaxf(pm, __shfl_xor(pm, 2, 64));
    pm = fmaxf(pm, __shfl_xor(pm, 4, 64));
    pm = fmaxf(pm, __shfl_xor(pm, 8, 64));
    m4[i] = pm;
  }
  if (lo == 0) {
#pragma unroll
    for (int i = 0; i < 4; ++i) redm[(wv << 4) + rb + i] = m4[i];
  }
  WAITL0(); SCHED0(); BARRIER();
#pragma unroll
  for (int i = 0; i < 4; ++i) {
    float m = redm[rb + i];
#pragma unroll
    for (int w = 1; w < 8; ++w) m = fmaxf(m, redm[(w << 4) + rb + i]);
    m4[i] = m;
  }
#pragma unroll
  for (int i = 0; i < 4; ++i) {
    float pl = 0.f;
#pragma unroll
    for (int kc = 0; kc < 8; ++kc) {
      float e = __expf(sacc[kc][i] - m4[i]);
      sacc[kc][i] = e;
      pl += e;
    }
    pl += __shfl_xor(pl, 1, 64);
    pl += __shfl_xor(pl, 2, 64);
    pl += __shfl_xor(pl, 4, 64);
    pl += __shfl_xor(pl, 8, 64);
    inv4[i] = pl;
  }
  if (lo == 0) {
#pragma unroll
    for (int i = 0; i < 4; ++i) redl[(wv << 4) + rb + i] = inv4[i];
  }
  WAITL0(); SCHED0(); BARRIER();
#pragma unroll
  for (int i = 0; i < 4; ++i) {
    float l = redl[rb + i];
#pragma unroll
    for (int w = 1; w < 8; ++w) l += redl[(w << 4) + rb + i];
    inv4[i] = 1.f / l;
  }
  // p -> bf16 LDS via HW cvt_pk
#pragma unroll
  for (int i = 0; i < 4; ++i) {
    int prow = (rb + i) * PBP + kr16;
    float iv = inv4[i];
#pragma unroll
    for (int k2 = 0; k2 < 4; ++k2) {
      unsigned u = cvtpk(sacc[2 * k2][i] * iv, sacc[2 * k2 + 1][i] * iv);
      pbs[prow + ((2 * k2) << 7)] = (unsigned short)u;
      pbs[prow + ((2 * k2 + 1) << 7)] = (unsigned short)(u >> 16);
    }
  }
  WAITL0();   // pbs writes complete before the V loop's first barrier publishes them

  // ---- Phase 3: out = p @ V; p global write interleaved; counted vmcnt ----
  const int pA = lo * PBP + (hi << 3);          // A-frag base (shorts)
  const int prow_w = t >> 5, pc4 = (t & 31) * 4;
  const unsigned short* pbr = &pbs[prow_w * PBP + pc4];
  float* pgl = pp + ((size_t)bh * NQc + q0 + prow_w) * (size_t)NKc + pc4;
  f32x4 oacc = {0.f, 0.f, 0.f, 0.f};
#pragma unroll 1
  for (int vc = 8; vc < 16; ++vc) {
    const int cur = vc & 1;
    const int vc0 = vc - 8;
    // wait constants derived from issue order (see analysis): stores interleave from vc=9 on
    if (vc == 8)      { WAITV(4); }
    else if (vc == 15){ WAITV(1); }
    else              { WAITV(5); }
    SCHED0();
    BARRIER();                   // kv[cur] (V chunk vc0) ready for all
#pragma unroll
    for (int kt = 0; kt < 4; ++kt) {
      short8 af = *(const short8*)&pbs[pA + (vc0 << 7) + (kt << 5)];
      short8 bf = *(const short8*)&kv[cur][qoff[kt]];
      oacc = __builtin_amdgcn_mfma_f32_16x16x32_bf16(af, bf, oacc, 0, 0, 0);
    }
    // p global write for this chunk's 128 columns
    {
      unsigned long long u = *(const unsigned long long*)(pbr + (vc0 << 7));
      unsigned l32 = (unsigned)u, h32 = (unsigned)(u >> 32);
      float4 o;
      o.x = bfbits(l32 << 16);
      o.y = bfbits(l32 & 0xffff0000u);
      o.z = bfbits(h32 << 16);
      o.w = bfbits(h32 & 0xffff0000u);
      *(float4*)(pgl + (vc0 << 7)) = o;
    }
    WAITL0(); SCHED0();          // LDS reads of kv[cur] complete
    BARRIER();                   // everyone done reading kv[cur]
    if (vc0 + 2 < 8) {
#pragma unroll
      for (int r = 0; r < 4; ++r) gl16(vsrc[r] + ((vc0 + 2) << 7), (char*)&kv[cur][0] + boff[r]);
    }
  }

  // ---- out[b,h,q,d] ----
#pragma unroll
  for (int i = 0; i < 4; ++i)
    outp[((size_t)bh * NQc + q0 + rb + i) * DHc + kr16] = oacc[i];
}

extern "C" void kernel_launch(void* const* d_in, const int* in_sizes, int n_in,
                              void* d_out, int out_size, void* d_ws, size_t ws_size,
                              hipStream_t stream) {
  (void)in_sizes; (void)n_in; (void)out_size; (void)ws_size;
  const float* q   = (const float*)d_in[0];
  const float* k   = (const float*)d_in[1];
  const float* v   = (const float*)d_in[2];
  const float* dq  = (const float*)d_in[4];
  const float* dkt = (const float*)d_in[5];
  const float* dkb = (const float*)d_in[6];
  const float* dks = (const float*)d_in[7];
  const float* ww  = (const float*)d_in[8];
  const float* bw  = (const float*)d_in[9];
  const float* wb  = (const float*)d_in[10];
  const float* bb  = (const float*)d_in[11];
  float* outp = (float*)d_out;
  float* pp   = outp + (size_t)Bc * Hc * NQc * DHc;

  unsigned short* kbf = (unsigned short*)d_ws;          // 8.39 MB
  unsigned short* vtb = kbf + KBF_ELEMS;                // 8.39 MB

  hipLaunchKernelGGL(prep, dim3(3072), dim3(256), 0, stream, k, v, kbf, vtb);
  hipLaunchKernelGGL(attn_main, dim3(2048), dim3(512), 0, stream,
                     q, kbf, vtb, dq, dkt, dkb, dks, ww, bw, wb, bb, outp, pp);
}

// Round 9
// 257.944 us; speedup vs baseline: 1.2376x; 1.2376x over previous
//
#include <hip/hip_runtime.h>

typedef short short8 __attribute__((ext_vector_type(8)));
typedef float f32x4 __attribute__((ext_vector_type(4)));

constexpr int Bc = 2, Hc = 16, NQc = 1024, NKc = 1024, DHc = 128;
constexpr int BQ = 16;
constexpr int PBP = 136;    // pb pitch (shorts): 272B rows, 16B-aligned, 2-way max bank spread
constexpr size_t FRAG_ELEMS = (size_t)Bc * Hc * NKc * DHc;   // 4,194,304 shorts per buffer

#define BARRIER() __builtin_amdgcn_s_barrier()
#define WAITL0() asm volatile("s_waitcnt lgkmcnt(0)" ::: "memory")
#define SCHED0() __builtin_amdgcn_sched_barrier(0)

__device__ __forceinline__ unsigned cvtpk(float a, float b) {  // HW RNE f32x2 -> bf16x2
  unsigned r;
  asm("v_cvt_pk_bf16_f32 %0, %1, %2" : "=v"(r) : "v"(a), "v"(b));
  return r;
}
__device__ __forceinline__ unsigned long long pack4(float a, float b, float c, float d) {
  return (unsigned long long)cvtpk(a, b) | ((unsigned long long)cvtpk(c, d) << 32);
}
__device__ __forceinline__ float bfbits(unsigned u) {  // u must be (bf16 << 16)
  union { unsigned x; float f; } w; w.x = u; return w.f;
}

// ---------------- pre-pass: K and V^T -> bf16 in MFMA-fragment-linear layout ----------------
// Fragment space per bh (131072 shorts): seg(chunk,kk,wv,lane) = ((chunk*4+kk)*8+wv)*64 + lane.
// K seg bytes  = K[chunk*128 + wv*16 + (lane&15)][kk*32 + (lane>>4)*8 + 0..7]
// V seg bytes  = V[chunk*128 + kk*32 + (lane>>4)*8 + 0..7][wv*16 + (lane&15)]  (i.e. V^T rows = d)
__global__ __launch_bounds__(256) void prep(const float* __restrict__ km,
                                            const float* __restrict__ vm,
                                            unsigned short* __restrict__ kf2,
                                            unsigned short* __restrict__ vf2) {
  const int blk = blockIdx.x, t = threadIdx.x;
  if (blk < 1024) {
    // V-fragment pass: 64x64 f32 tile transpose via LDS, emit fragment-linear bf16
    __shared__ float tile[64][65];
    const int bh = blk >> 5, tl = blk & 31;
    const int k0 = (tl & 15) * 64, d0 = (tl >> 4) * 64;
    const float* vsrc = vm + ((size_t)bh * NKc + k0) * DHc + d0;
    {
      int j = t & 63, i0 = t >> 6;
#pragma unroll
      for (int s = 0; s < 16; ++s) {
        int i = i0 + s * 4;
        tile[i][j] = vsrc[(size_t)i * DHc + j];
      }
    }
    __syncthreads();
    const int vc = k0 >> 7, ktb = (k0 >> 5) & 3, wvb = d0 >> 4;
    unsigned short* vdst = vf2 + ((size_t)bh << 17);   // 131072 shorts per bh (BUG FIX: was <<14)
#pragma unroll
    for (int s2 = 0; s2 < 2; ++s2) {
      int ts = s2 * 256 + t;                    // 0..511
      int wvl = ts >> 7, ktl = (ts >> 6) & 1, hii = (ts >> 4) & 3, loo = ts & 15;
      int seg = ((vc * 4 + ktb + ktl) * 8 + wvb + wvl) * 64 + (hii << 4) + loo;
      int kl = ktl * 32 + hii * 8;
      int dl = wvl * 16 + loo;
      float a0 = tile[kl + 0][dl], a1 = tile[kl + 1][dl], a2 = tile[kl + 2][dl], a3 = tile[kl + 3][dl];
      float a4 = tile[kl + 4][dl], a5 = tile[kl + 5][dl], a6 = tile[kl + 6][dl], a7 = tile[kl + 7][dl];
      unsigned long long u0 = pack4(a0, a1, a2, a3), u1 = pack4(a4, a5, a6, a7);
      *(unsigned long long*)(vdst + (size_t)seg * 8) = u0;
      *(unsigned long long*)(vdst + (size_t)seg * 8 + 4) = u1;
    }
  } else {
    // K-fragment pass: one block per (bh, chunk)
    const int blk2 = blk - 1024;
    const int bh = blk2 >> 3, kc = blk2 & 7;
    const float* ks = km + ((size_t)bh * NKc + kc * 128) * DHc;
    unsigned short* kdst = kf2 + ((size_t)(bh * 8 + kc)) * 16384;
#pragma unroll
    for (int s8 = 0; s8 < 8; ++s8) {
      int s = s8 * 256 + t;                     // 0..2047
      int kk = s >> 9, wvv = (s >> 6) & 7, hii = (s >> 4) & 3, loo = s & 15;
      const float* sp = ks + (size_t)(wvv * 16 + loo) * DHc + kk * 32 + hii * 8;
      float4 A = *(const float4*)sp, B4 = *(const float4*)(sp + 4);
      unsigned long long u0 = pack4(A.x, A.y, A.z, A.w), u1 = pack4(B4.x, B4.y, B4.z, B4.w);
      *(unsigned long long*)(kdst + (size_t)s * 8) = u0;
      *(unsigned long long*)(kdst + (size_t)s * 8 + 4) = u1;
    }
  }
}

// ---------------- main fused attention: barrier-free K/V reg streaming ----------------
__global__ __launch_bounds__(512, 4) void attn_main(
    const float* __restrict__ qm, const unsigned short* __restrict__ kf2,
    const unsigned short* __restrict__ vf2,
    const float* __restrict__ dq, const float* __restrict__ dkt, const float* __restrict__ dkb,
    const float* __restrict__ dks, const float* __restrict__ ww, const float* __restrict__ bw,
    const float* __restrict__ wb, const float* __restrict__ bb,
    float* __restrict__ outp, float* __restrict__ pp)
{
  __shared__ __align__(16) unsigned short pb[2][BQ * PBP];   // 8.7 KB p-chunk transpose dbuf
  __shared__ float e0s[1024], cws[1024], cbs[1024];          // 12 KB gate scalars
  __shared__ float aws[BQ], abs_[BQ];
  __shared__ float redm[128], redl[128];
  // total ~22 KB LDS; occupancy VGPR-capped

  const int wg = blockIdx.x;
  const int bid = (wg & 7) * 256 + (wg >> 3);   // bijective XCD swizzle (2048 % 8 == 0)
  const int qt = bid & 63, h = (bid >> 6) & 15, b = bid >> 10;
  const int q0 = qt * BQ;
  const int t = threadIdx.x, wv = t >> 6, lane = t & 63;
  const int hi = lane >> 4, lo = lane & 15;
  const int rb = hi << 2;
  const int bh = b * Hc + h;
  const int kr16 = (wv << 4) + lo;              // B-frag n (key idx / out-dim idx)

  // per-lane fragment base pointers (shorts)
  const unsigned short* kfb = kf2 + ((size_t)bh << 17) + (((wv << 6) + lane) << 3);
  const unsigned short* vfb = vf2 + ((size_t)bh << 17) + (((wv << 6) + lane) << 3);  // BUG FIX: was <<14

  // ---- early issue: K chunk 0 fragments + Q rows (fly under gate precompute) ----
  short8 kf[2][4];
#pragma unroll
  for (int kk = 0; kk < 4; ++kk)
    kf[0][kk] = *(const short8*)(kfb + (kk << 12));

  short8 qf[4];
  {
    const float* qg = qm + ((size_t)bh * NQc + q0 + lo) * DHc + hi * 8;
#pragma unroll
    for (int kk = 0; kk < 4; ++kk) {
      float4 a = *(const float4*)(qg + kk * 32);
      float4 c = *(const float4*)(qg + kk * 32 + 4);
      union { short8 v; unsigned long long u[2]; } q8;
      q8.u[0] = pack4(a.x, a.y, a.z, a.w);
      q8.u[1] = pack4(c.x, c.y, c.z, c.w);
      qf[kk] = q8.v;
    }
  }

  // ---- gate scalar precompute ----
  {
    float whc[8], wbc[8];
#pragma unroll
    for (int d = 0; d < 8; ++d) { whc[d] = ww[d * Hc + h]; wbc[d] = wb[d * Hc + h]; }
    float bwh = bw[h], bbh = bb[h];
#pragma unroll
    for (int rep = 0; rep < 2; ++rep) {
      int kk = t + rep * 512;
      const float* sc = dks + ((size_t)b * NKc + kk) * 2;
      float s0 = sc[0], s1 = sc[1];
      const float* tp = dkt + ((size_t)b * NKc + kk) * 8;
      const float* bp = dkb + ((size_t)b * NKc + kk) * 8;
      float4 t0 = *(const float4*)tp, t1 = *(const float4*)(tp + 4);
      float4 b0 = *(const float4*)bp, b1 = *(const float4*)(bp + 4);
      float tv[8] = {t0.x, t0.y, t0.z, t0.w, t1.x, t1.y, t1.z, t1.w};
      float bv[8] = {b0.x, b0.y, b0.z, b0.w, b1.x, b1.y, b1.z, b1.w};
      float cw = 0.f, cb = 0.f;
#pragma unroll
      for (int d = 0; d < 8; ++d) {
        float dk = tv[d] * s0 + bv[d] * s1;
        cw += dk * whc[d];
        cb += dk * wbc[d];
      }
      e0s[kk] = s0 + s1;
      cws[kk] = cw - bwh;
      cbs[kk] = cb - bbh;
    }
    if (t < BQ) {
      const float* dqr = dq + ((size_t)b * NQc + q0 + t) * 8;
      float4 a = *(const float4*)dqr, b4 = *(const float4*)(dqr + 4);
      float dv[8] = {a.x, a.y, a.z, a.w, b4.x, b4.y, b4.z, b4.w};
      float saw = 0.f, sab = 0.f;
#pragma unroll
      for (int d = 0; d < 8; ++d) { saw += dv[d] * whc[d]; sab += dv[d] * wbc[d]; }
      aws[t] = saw; abs_[t] = sab;
    }
  }
  WAITL0(); SCHED0(); BARRIER();   // gate scalars visible (raw barrier: K prefetch stays in flight)

  float aw4[4], ab4[4];
#pragma unroll
  for (int i = 0; i < 4; ++i) { aw4[i] = aws[rb + i]; ab4[i] = abs_[rb + i]; }

  const float scale = 0.08838834764831845f;  // 1/sqrt(128)

  // ---- Phase 1: QK^T + gate, barrier-free register streaming ----
  f32x4 sacc[8];
#pragma unroll
  for (int kc = 0; kc < 8; ++kc) {
    if (kc < 7) {
#pragma unroll
      for (int kk = 0; kk < 4; ++kk)
        kf[(kc & 1) ^ 1][kk] = *(const short8*)(kfb + ((((kc + 1) << 2) + kk) << 12));
    }
    f32x4 acc = {0.f, 0.f, 0.f, 0.f};
#pragma unroll
    for (int kk = 0; kk < 4; ++kk)
      acc = __builtin_amdgcn_mfma_f32_16x16x32_bf16(qf[kk], kf[kc & 1][kk], acc, 0, 0, 0);
    int cg = (kc << 7) + kr16;
    float e0 = e0s[cg], cw2 = cws[cg], cb2 = cbs[cg];
#pragma unroll
    for (int i = 0; i < 4; ++i) {
      float s = acc[i] * scale;
      float x = fmaf(e0, aw4[i], -cw2);
      float ex = __expf(x);
      float sp = (x > 20.f) ? x : __logf(1.f + ex);   // softplus, cheap form
      acc[i] = fmaf(s, sp, fmaf(e0, ab4[i], -cb2));
    }
    sacc[kc] = acc;
  }

  // ---- issue V chunk 0 now: flies under the softmax ----
  short8 vf[2][4];
#pragma unroll
  for (int kt = 0; kt < 4; ++kt)
    vf[0][kt] = *(const short8*)(vfb + (kt << 12));

  // ---- Phase 2: exact softmax over registers ----
  float m4[4], inv4[4];
#pragma unroll
  for (int i = 0; i < 4; ++i) {
    float pm = sacc[0][i];
#pragma unroll
    for (int kc = 1; kc < 8; ++kc) pm = fmaxf(pm, sacc[kc][i]);
    pm = fmaxf(pm, __shfl_xor(pm, 1, 64));
    pm = fmaxf(pm, __shfl_xor(pm, 2, 64));
    pm = fmaxf(pm, __shfl_xor(pm, 4, 64));
    pm = fmaxf(pm, __shfl_xor(pm, 8, 64));
    m4[i] = pm;
  }
  if (lo == 0) {
#pragma unroll
    for (int i = 0; i < 4; ++i) redm[(wv << 4) + rb + i] = m4[i];
  }
  WAITL0(); SCHED0(); BARRIER();
#pragma unroll
  for (int i = 0; i < 4; ++i) {
    float m = redm[rb + i];
#pragma unroll
    for (int w = 1; w < 8; ++w) m = fmaxf(m, redm[(w << 4) + rb + i]);
    m4[i] = m;
  }
#pragma unroll
  for (int i = 0; i < 4; ++i) {
    float pl = 0.f;
#pragma unroll
    for (int kc = 0; kc < 8; ++kc) {
      float e = __expf(sacc[kc][i] - m4[i]);
      sacc[kc][i] = e;
      pl += e;
    }
    pl += __shfl_xor(pl, 1, 64);
    pl += __shfl_xor(pl, 2, 64);
    pl += __shfl_xor(pl, 4, 64);
    pl += __shfl_xor(pl, 8, 64);
    inv4[i] = pl;
  }
  if (lo == 0) {
#pragma unroll
    for (int i = 0; i < 4; ++i) redl[(wv << 4) + rb + i] = inv4[i];
  }
  WAITL0(); SCHED0(); BARRIER();
#pragma unroll
  for (int i = 0; i < 4; ++i) {
    float l = redl[rb + i];
#pragma unroll
    for (int w = 1; w < 8; ++w) l += redl[(w << 4) + rb + i];
    inv4[i] = 1.f / l;
  }

  // ---- Phase 3: out = p @ V; one lgkm-only barrier per chunk; V streams in regs ----
  const int prow_w = t >> 5, pc4 = (t & 31) * 4;
  float* pgl = pp + ((size_t)bh * NQc + q0 + prow_w) * (size_t)NKc + pc4;
  f32x4 oacc = {0.f, 0.f, 0.f, 0.f};
#pragma unroll
  for (int vc = 0; vc < 8; ++vc) {
    if (vc < 7) {
#pragma unroll
      for (int kt = 0; kt < 4; ++kt)
        vf[(vc & 1) ^ 1][kt] = *(const short8*)(vfb + ((((vc + 1) << 2) + kt) << 12));
    }
    // p-global write for chunk vc-1 from pb[(vc-1)&1] (visible since before previous barrier)
    if (vc > 0) {
      unsigned long long u = *(const unsigned long long*)&pb[(vc + 1) & 1][prow_w * PBP + pc4];
      unsigned l32 = (unsigned)u, h32 = (unsigned)(u >> 32);
      float4 o;
      o.x = bfbits(l32 << 16);
      o.y = bfbits(l32 & 0xffff0000u);
      o.z = bfbits(h32 << 16);
      o.w = bfbits(h32 & 0xffff0000u);
      *(float4*)(pgl + ((vc - 1) << 7)) = o;
    }
    // write pb[vc&1] <- normalized p chunk vc (thread owns rows rb..rb+3, col kr16)
    {
      unsigned u01 = cvtpk(sacc[vc][0] * inv4[0], sacc[vc][1] * inv4[1]);
      unsigned u23 = cvtpk(sacc[vc][2] * inv4[2], sacc[vc][3] * inv4[3]);
      pb[vc & 1][(rb + 0) * PBP + kr16] = (unsigned short)u01;
      pb[vc & 1][(rb + 1) * PBP + kr16] = (unsigned short)(u01 >> 16);
      pb[vc & 1][(rb + 2) * PBP + kr16] = (unsigned short)u23;
      pb[vc & 1][(rb + 3) * PBP + kr16] = (unsigned short)(u23 >> 16);
    }
    WAITL0(); SCHED0(); BARRIER();   // pb[vc&1] visible; no vmcnt drain (V loads in flight)
#pragma unroll
    for (int kt = 0; kt < 4; ++kt) {
      short8 af = *(const short8*)&pb[vc & 1][lo * PBP + (kt << 5) + (hi << 3)];
      oacc = __builtin_amdgcn_mfma_f32_16x16x32_bf16(af, vf[vc & 1][kt], oacc, 0, 0, 0);
    }
  }
  // final p-global write for chunk 7 from pb[1] (visible post last barrier)
  {
    unsigned long long u = *(const unsigned long long*)&pb[1][prow_w * PBP + pc4];
    unsigned l32 = (unsigned)u, h32 = (unsigned)(u >> 32);
    float4 o;
    o.x = bfbits(l32 << 16);
    o.y = bfbits(l32 & 0xffff0000u);
    o.z = bfbits(h32 << 16);
    o.w = bfbits(h32 & 0xffff0000u);
    *(float4*)(pgl + (7 << 7)) = o;
  }

  // ---- out[b,h,q,d] ----
#pragma unroll
  for (int i = 0; i < 4; ++i)
    outp[((size_t)bh * NQc + q0 + rb + i) * DHc + kr16] = oacc[i];
}

extern "C" void kernel_launch(void* const* d_in, const int* in_sizes, int n_in,
                              void* d_out, int out_size, void* d_ws, size_t ws_size,
                              hipStream_t stream) {
  (void)in_sizes; (void)n_in; (void)out_size; (void)ws_size;
  const float* q   = (const float*)d_in[0];
  const float* k   = (const float*)d_in[1];
  const float* v   = (const float*)d_in[2];
  const float* dq  = (const float*)d_in[4];
  const float* dkt = (const float*)d_in[5];
  const float* dkb = (const float*)d_in[6];
  const float* dks = (const float*)d_in[7];
  const float* ww  = (const float*)d_in[8];
  const float* bw  = (const float*)d_in[9];
  const float* wb  = (const float*)d_in[10];
  const float* bb  = (const float*)d_in[11];
  float* outp = (float*)d_out;
  float* pp   = outp + (size_t)Bc * Hc * NQc * DHc;

  unsigned short* kf2 = (unsigned short*)d_ws;          // 8.39 MB fragment-linear K
  unsigned short* vf2 = kf2 + FRAG_ELEMS;               // 8.39 MB fragment-linear V^T

  hipLaunchKernelGGL(prep, dim3(1280), dim3(256), 0, stream, k, v, kf2, vf2);
  hipLaunchKernelGGL(attn_main, dim3(2048), dim3(512), 0, stream,
                     q, kf2, vf2, dq, dkt, dkb, dks, ww, bw, wb, bb, outp, pp);
}